// Round 3
// baseline (838.339 us; speedup 1.0000x reference)
//
#include <hip/hip_runtime.h>

typedef short s16x8 __attribute__((ext_vector_type(8)));
typedef float f32x16 __attribute__((ext_vector_type(16)));

__device__ __forceinline__ unsigned int f2b(float f) {
    union { float f; unsigned int u; } x; x.f = f;
    unsigned int r = x.u + 0x7FFFu + ((x.u >> 16) & 1u);
    return r >> 16;
}
__device__ __forceinline__ float b2f(unsigned int h) {
    union { unsigned int u; float f; } x; x.u = h << 16; return x.f;
}
// 8 consecutive fp32 -> 8 bf16 lanes (RNE)
__device__ __forceinline__ s16x8 cvt8(const float* p) {
    float4 a = *(const float4*)p;
    float4 b = *(const float4*)(p + 4);
    s16x8 r;
    r[0] = (short)f2b(a.x); r[1] = (short)f2b(a.y);
    r[2] = (short)f2b(a.z); r[3] = (short)f2b(a.w);
    r[4] = (short)f2b(b.x); r[5] = (short)f2b(b.y);
    r[6] = (short)f2b(b.z); r[7] = (short)f2b(b.w);
    return r;
}

// ---------------------------------------------------------------------------
// fp32 NCHW (Nb,128,64,64) -> bf16 NHWC (Nb,64,64,128), optional per-(n,c)
// scale/shift (AdaIN). apply==0 => plain cast+transpose. Local n everywhere.
// grid = Nb*64 (one block per (n,h)), 256 threads.
// ---------------------------------------------------------------------------
__global__ __launch_bounds__(256) void k_norm_transpose(
    const float* __restrict__ src,
    unsigned short* __restrict__ dst,
    const float2* __restrict__ scsh,
    int apply)
{
    __shared__ unsigned int tile[128 * 66];
    int b = blockIdx.x;
    int n = b >> 6, h = b & 63;
    int tid = threadIdx.x;
    #pragma unroll
    for (int i = 0; i < 8; ++i) {
        int u = tid + i * 256;              // u < 2048
        int c = u >> 4, w0 = (u & 15) * 4;
        float2 sc = apply ? scsh[n * 128 + c] : make_float2(1.f, 0.f);
        float4 v = *(const float4*)(src + ((n * 128 + c) * 4096 + h * 64 + w0));
        tile[c * 66 + w0 + 0] = f2b(v.x * sc.x + sc.y);
        tile[c * 66 + w0 + 1] = f2b(v.y * sc.x + sc.y);
        tile[c * 66 + w0 + 2] = f2b(v.z * sc.x + sc.y);
        tile[c * 66 + w0 + 3] = f2b(v.w * sc.x + sc.y);
    }
    __syncthreads();
    #pragma unroll
    for (int i = 0; i < 32; ++i) {
        int idx = tid + i * 256;            // idx < 8192
        int c = idx & 127, w = idx >> 7;
        dst[((n * 64 + h) * 64 + w) * 128 + c] = (unsigned short)tile[c * 66 + w];
    }
}

// ---------------------------------------------------------------------------
// Modulation GEMM (fp32 in, bf16 MFMA, fp32 acc) + weight repack + bias GEMM.
// blocks 0..255:  gb = task @ (t_w/16)^T + t_b, then
//                 Wmod[n][tap][o*128+i] = bf16((W*gamma + beta)/24)
// blocks 256..287: bias[n][oc] = b[oc] + task[n].tb_w[oc]/16 + tb_b[oc]
// ---------------------------------------------------------------------------
__global__ __launch_bounds__(256) void k_modbias(
    const float* __restrict__ t_w,   // (32768,512)
    const float* __restrict__ t_b,   // (32768)
    const float* __restrict__ Wc,    // (128,128,3,3)
    const float* __restrict__ tb_w,  // (128,512)
    const float* __restrict__ tb_b,  // (128)
    const float* __restrict__ bconv, // (128)
    const float* __restrict__ task,  // (32,512)
    unsigned short* __restrict__ Wmod, // (32,9,128,128) bf16
    float* __restrict__ bias)          // (32,128)
{
    __shared__ float gb[32 * 130];
    __shared__ float red[256];
    int blk = blockIdx.x;
    int tid = threadIdx.x;

    if (blk < 256) {
        int wv = tid >> 6, lane = tid & 63, l31 = lane & 31, lhalf = lane >> 5;
        int rbase = blk * 128 + wv * 32;
        const float* Ap = t_w + (size_t)(rbase + l31) * 512 + lhalf * 8;
        const float* Bp = task + l31 * 512 + lhalf * 8;
        f32x16 acc;
        #pragma unroll
        for (int e = 0; e < 16; ++e) acc[e] = 0.f;
        for (int k0 = 0; k0 < 512; k0 += 16) {
            s16x8 a = cvt8(Ap + k0);
            s16x8 b = cvt8(Bp + k0);
            acc = __builtin_amdgcn_mfma_f32_32x32x16_bf16(a, b, acc, 0, 0, 0);
        }
        // D: col(sample)=lane&31, row=(reg&3)+8*(reg>>2)+4*(lane>>5)
        int nn = l31;
        #pragma unroll
        for (int reg = 0; reg < 16; ++reg) {
            int rl = wv * 32 + (reg & 3) + 8 * (reg >> 2) + 4 * lhalf;
            gb[nn * 130 + rl] = acc[reg] * 0.0625f + t_b[blk * 128 + rl];
        }
        __syncthreads();
        for (int it = 0; it < 72; ++it) {
            int u = tid + it * 256;          // < 18432 = 32n*9tap*64oi
            int n2 = u / 576;
            int rem = u - n2 * 576;
            int tap = rem >> 6, oi = rem & 63;
            int oig = blk * 64 + oi;         // = o*128 + i
            float gamma = gb[n2 * 130 + 2 * oi];
            float beta  = gb[n2 * 130 + 2 * oi + 1];
            float val = (Wc[oig * 9 + tap] * gamma + beta) * (1.0f / 24.0f);
            Wmod[(n2 * 9 + tap) * 16384 + oig] = (unsigned short)f2b(val);
        }
    } else {
        int n = blk - 256;
        int c = tid & 127, h2 = tid >> 7;
        const float* tw = tb_w + c * 512 + h2 * 256;
        const float* tk = task + n * 512 + h2 * 256;
        float s = 0.f;
        for (int k0 = 0; k0 < 256; k0 += 4) {
            float4 a = *(const float4*)(tw + k0);
            float4 b = *(const float4*)(tk + k0);
            s += a.x * b.x + a.y * b.y + a.z * b.z + a.w * b.w;
        }
        red[tid] = s;
        __syncthreads();
        if (tid < 128)
            bias[n * 128 + tid] = bconv[tid] + (red[tid] + red[tid + 128]) * 0.0625f
                                + tb_b[tid];
    }
}

// ---------------------------------------------------------------------------
// Per-sample modulated 3x3 conv (pad 1) + bias + noise + leakyReLU.
// xT bf16 NHWC (local n), Wmod bf16, bias/nzw/noise fp32, y fp32 NCHW.
// grid = Nb*16 (4 output rows per block). Wave tile 64oc x 128pix.
// LDS [6 rows][66 wslots][32 ci] bf16, XOR-swizzled 16B blocks.
// ---------------------------------------------------------------------------
__global__ __launch_bounds__(256, 2) void k_conv(
    const unsigned short* __restrict__ xT,
    const unsigned short* __restrict__ Wmod,
    const float* __restrict__ bias,
    const float* __restrict__ nzw,
    const float* __restrict__ noise,
    float* __restrict__ y)
{
    __shared__ __align__(16) unsigned short xs[6 * 66 * 32];
    int blk = blockIdx.x;
    int n = blk >> 4, r0 = (blk & 15) * 4;
    int tid = threadIdx.x;
    int wv = tid >> 6, lane = tid & 63, l31 = lane & 31, lhalf = lane >> 5;
    int ochalf = wv & 1, pixhalf = wv >> 1;

    f32x16 acc[2][4];
    #pragma unroll
    for (int a = 0; a < 2; ++a)
        #pragma unroll
        for (int t = 0; t < 4; ++t)
            #pragma unroll
            for (int e = 0; e < 16; ++e) acc[a][t][e] = 0.f;

    for (int cic = 0; cic < 4; ++cic) {
        __syncthreads();
        #pragma unroll
        for (int i = 0; i < 7; ++i) {
            int u = tid + i * 256;
            if (u < 1584) {                    // 6 rows * 66 wsl * 4 blocks
                int row = u / 264;
                int rem = u - row * 264;
                int wsl = rem >> 2, bb = rem & 3;
                int h = r0 - 1 + row, wg = wsl - 1;
                uint4 v = make_uint4(0u, 0u, 0u, 0u);
                if (h >= 0 && h < 64 && wg >= 0 && wg < 64)
                    v = *(const uint4*)(xT + (((n * 64 + h) * 64 + wg) * 128 + cic * 32 + bb * 8));
                int bs = bb ^ ((wsl >> 1) & 3);
                *(uint4*)((char*)xs + (row * 66 + wsl) * 64 + bs * 16) = v;
            }
        }
        __syncthreads();
        #pragma unroll
        for (int kh = 0; kh < 3; ++kh) {
            #pragma unroll
            for (int kw = 0; kw < 3; ++kw) {
                const unsigned short* wp = Wmod + (n * 9 + kh * 3 + kw) * 16384;
                #pragma unroll
                for (int ks = 0; ks < 2; ++ks) {
                    int ci = cic * 32 + ks * 16 + lhalf * 8;
                    s16x8 A0 = *(const s16x8*)(wp + (ochalf * 64 + l31) * 128 + ci);
                    s16x8 A1 = *(const s16x8*)(wp + (ochalf * 64 + 32 + l31) * 128 + ci);
                    int bb = ks * 2 + lhalf;
                    s16x8 Bf[4];
                    #pragma unroll
                    for (int t = 0; t < 4; ++t) {
                        int rl = pixhalf * 2 + (t >> 1) + kh;
                        int wsl = (t & 1) * 32 + l31 + kw;
                        int bs = bb ^ ((wsl >> 1) & 3);
                        Bf[t] = *(const s16x8*)((const char*)xs + (rl * 66 + wsl) * 64 + bs * 16);
                    }
                    #pragma unroll
                    for (int t = 0; t < 4; ++t) {
                        acc[0][t] = __builtin_amdgcn_mfma_f32_32x32x16_bf16(A0, Bf[t], acc[0][t], 0, 0, 0);
                        acc[1][t] = __builtin_amdgcn_mfma_f32_32x32x16_bf16(A1, Bf[t], acc[1][t], 0, 0, 0);
                    }
                }
            }
        }
    }
    #pragma unroll
    for (int a = 0; a < 2; ++a) {
        int ocb = ochalf * 64 + a * 32;
        float bv[16], nzv[16];
        #pragma unroll
        for (int reg = 0; reg < 16; ++reg) {
            int oc = ocb + (reg & 3) + 8 * (reg >> 2) + 4 * lhalf;
            bv[reg] = bias[n * 128 + oc];
            nzv[reg] = nzw[oc] * 0.125f;
        }
        #pragma unroll
        for (int t = 0; t < 4; ++t) {
            int r = r0 + pixhalf * 2 + (t >> 1);
            int wq = (t & 1) * 32 + l31;
            float nv = noise[(n * 64 + r) * 64 + wq];
            #pragma unroll
            for (int reg = 0; reg < 16; ++reg) {
                int oc = ocb + (reg & 3) + 8 * (reg >> 2) + 4 * lhalf;
                float v = acc[a][t][reg] + bv[reg] + nzv[reg] * nv;
                v = v > 0.f ? v : 0.2f * v;
                y[(size_t)(n * 128 + oc) * 4096 + r * 64 + wq] = v;
            }
        }
    }
}

// ---------------------------------------------------------------------------
// Per-(n,c) sum / sum-sq over 4096 fp32. grid = Nb*128 (local n).
// ---------------------------------------------------------------------------
__global__ __launch_bounds__(256) void k_stats(
    const float* __restrict__ y, float2* __restrict__ stats)
{
    __shared__ float rs[4], rs2[4];
    int blk = blockIdx.x, tid = threadIdx.x;
    const float4* p = (const float4*)(y + (size_t)blk * 4096) + tid * 4;
    float s = 0.f, s2 = 0.f;
    #pragma unroll
    for (int j = 0; j < 4; ++j) {
        float4 v = p[j];
        s  += v.x + v.y + v.z + v.w;
        s2 += v.x * v.x + v.y * v.y + v.z * v.z + v.w * v.w;
    }
    #pragma unroll
    for (int off = 32; off > 0; off >>= 1) {
        s  += __shfl_down(s, off);
        s2 += __shfl_down(s2, off);
    }
    int wv = tid >> 6;
    if ((tid & 63) == 0) { rs[wv] = s; rs2[wv] = s2; }
    __syncthreads();
    if (tid == 0)
        stats[blk] = make_float2(rs[0] + rs[1] + rs[2] + rs[3],
                                 rs2[0] + rs2[1] + rs2[2] + rs2[3]);
}

// ---------------------------------------------------------------------------
// Style GEMM (Nb samples x 256 rows, K=512, fp32) + instance-norm finalize.
// grid = Nb (local n; pointers pre-offset).
// ---------------------------------------------------------------------------
__global__ __launch_bounds__(256) void k_finstyle(
    const float* __restrict__ style, // (Nb,512)
    const float* __restrict__ ad_w,  // (256,512)
    const float* __restrict__ ad_b,  // (256)
    const float2* __restrict__ stats,
    float2* __restrict__ scsh)
{
    __shared__ float styl[512];
    __shared__ float sbuf[256];
    int n = blockIdx.x, tid = threadIdx.x;
    styl[tid]       = style[n * 512 + tid];
    styl[tid + 256] = style[n * 512 + 256 + tid];
    __syncthreads();
    const float* wr = ad_w + tid * 512;
    float dot = 0.f;
    for (int k0 = 0; k0 < 512; k0 += 4) {
        float4 a = *(const float4*)(wr + k0);
        dot += a.x * styl[k0] + a.y * styl[k0 + 1] + a.z * styl[k0 + 2] + a.w * styl[k0 + 3];
    }
    sbuf[tid] = dot * 0.0625f + ad_b[tid];
    __syncthreads();
    if (tid < 128) {
        float gamma = sbuf[tid], beta = sbuf[128 + tid];
        float2 st = stats[n * 128 + tid];
        float mu = st.x * (1.f / 4096.f);
        float var = st.y * (1.f / 4096.f) - mu * mu;
        float rstd = rsqrtf(var + 1e-5f);
        float scale = gamma * rstd;
        scsh[n * 128 + tid] = make_float2(scale, beta - mu * scale);
    }
}

// ---------------------------------------------------------------------------
// Final AdaIN normalize fp32 NCHW -> fp32 NCHW. Local n; 4 floats/thread.
// ---------------------------------------------------------------------------
__global__ __launch_bounds__(256) void k_norm_out(
    const float* __restrict__ y,
    const float2* __restrict__ scsh,
    float* __restrict__ out)
{
    int idx = blockIdx.x * 256 + threadIdx.x;
    size_t base = (size_t)idx * 4;
    int c = (int)((base >> 12) & 127);
    int n = (int)(base >> 19);
    float2 sc = scsh[n * 128 + c];
    float4 v = *(const float4*)(y + base);
    float4 o;
    o.x = v.x * sc.x + sc.y; o.y = v.y * sc.x + sc.y;
    o.z = v.z * sc.x + sc.y; o.w = v.w * sc.x + sc.y;
    *(float4*)(out + base) = o;
}

// ---------------------------------------------------------------------------
extern "C" void kernel_launch(void* const* d_in, const int* in_sizes, int n_in,
                              void* d_out, int out_size, void* d_ws, size_t ws_size,
                              hipStream_t stream)
{
    const float* x     = (const float*)d_in[0];
    const float* style = (const float*)d_in[1];
    const float* noise = (const float*)d_in[2];
    const float* task  = (const float*)d_in[3];
    const float* W1    = (const float*)d_in[4];
    const float* b1    = (const float*)d_in[5];
    const float* t1w   = (const float*)d_in[6];
    const float* t1b   = (const float*)d_in[7];
    const float* tb1w  = (const float*)d_in[8];
    const float* tb1b  = (const float*)d_in[9];
    const float* nz1   = (const float*)d_in[10];
    const float* ad1w  = (const float*)d_in[11];
    const float* ad1b  = (const float*)d_in[12];
    const float* W2    = (const float*)d_in[13];
    const float* b2v   = (const float*)d_in[14];
    const float* t2w   = (const float*)d_in[15];
    const float* t2b   = (const float*)d_in[16];
    const float* tb2w  = (const float*)d_in[17];
    const float* tb2b  = (const float*)d_in[18];
    const float* nz2   = (const float*)d_in[19];
    const float* ad2w  = (const float*)d_in[20];
    const float* ad2b  = (const float*)d_in[21];
    float* outF = (float*)d_out;
    unsigned short* outU = (unsigned short*)d_out;  // bf16 NHWC staging inside d_out

    // Workspace: 26.3 MB
    char* ws = (char*)d_ws;
    unsigned short* WMOD  = (unsigned short*)(ws);            // 9,437,184 B (32 samples, bf16)
    float*          YQ    = (float*)(ws + 9437184);           // 16,777,216 B (8-sample fp32 NCHW)
    float*          BIAS  = (float*)(ws + 26214400);          // 16 KB
    float2*         STATS = (float2*)(ws + 26230784);         // 32 KB
    float2*         SCSH  = (float2*)(ws + 26263552);         // 32 KB

    const int NS  = 524288;   // per-sample NHWC elements
    const int WMS = 147456;   // per-sample Wmod elements

    // stage 0: fp32 NCHW x -> bf16 NHWC (all 32 samples) into d_out
    k_norm_transpose<<<2048, 256, 0, stream>>>(x, outU, nullptr, 0);

    // ---- layer 1 (quarters ascending; NHWC replaced in-place per quarter) ----
    k_modbias<<<288, 256, 0, stream>>>(t1w, t1b, W1, tb1w, tb1b, b1, task, WMOD, BIAS);
    for (int q = 0; q < 4; ++q) {
        int n0 = q * 8;
        k_conv<<<128, 256, 0, stream>>>(outU + (size_t)n0 * NS, WMOD + (size_t)n0 * WMS,
                                        BIAS + n0 * 128, nz1, noise + n0 * 4096, YQ);
        k_stats<<<1024, 256, 0, stream>>>(YQ, STATS + n0 * 128);
        k_finstyle<<<8, 256, 0, stream>>>(style + n0 * 512, ad1w, ad1b,
                                          STATS + n0 * 128, SCSH + n0 * 128);
        k_norm_transpose<<<512, 256, 0, stream>>>(YQ, outU + (size_t)n0 * NS,
                                                  SCSH + n0 * 128, 1);
    }

    // ---- layer 2 (quarters DESCENDING: fp32 outputs into d_out never clobber
    //      the bf16 NHWC regions still needed by lower quarters) ----
    k_modbias<<<288, 256, 0, stream>>>(t2w, t2b, W2, tb2w, tb2b, b2v, task, WMOD, BIAS);
    for (int q = 3; q >= 0; --q) {
        int n0 = q * 8;
        k_conv<<<128, 256, 0, stream>>>(outU + (size_t)n0 * NS, WMOD + (size_t)n0 * WMS,
                                        BIAS + n0 * 128, nz2, noise + n0 * 4096, YQ);
        k_stats<<<1024, 256, 0, stream>>>(YQ, STATS + n0 * 128);
        k_finstyle<<<8, 256, 0, stream>>>(style + n0 * 512, ad2w, ad2b,
                                          STATS + n0 * 128, SCSH + n0 * 128);
        k_norm_out<<<4096, 256, 0, stream>>>(YQ, SCSH + n0 * 128,
                                             outF + (size_t)n0 * NS);
    }
}

// Round 4
// 575.804 us; speedup vs baseline: 1.4559x; 1.4559x over previous
//
#include <hip/hip_runtime.h>

typedef short s16x8 __attribute__((ext_vector_type(8)));
typedef float f32x16 __attribute__((ext_vector_type(16)));

__device__ __forceinline__ unsigned int f2b(float f) {
    union { float f; unsigned int u; } x; x.f = f;
    unsigned int r = x.u + 0x7FFFu + ((x.u >> 16) & 1u);
    return r >> 16;
}
__device__ __forceinline__ float b2f(unsigned int h) {
    union { unsigned int u; float f; } x; x.u = h << 16; return x.f;
}
__device__ __forceinline__ s16x8 cvt8(const float* p) {
    float4 a = *(const float4*)p;
    float4 b = *(const float4*)(p + 4);
    s16x8 r;
    r[0] = (short)f2b(a.x); r[1] = (short)f2b(a.y);
    r[2] = (short)f2b(a.z); r[3] = (short)f2b(a.w);
    r[4] = (short)f2b(b.x); r[5] = (short)f2b(b.y);
    r[6] = (short)f2b(b.z); r[7] = (short)f2b(b.w);
    return r;
}

// ---------------------------------------------------------------------------
// fp32 NCHW (Nb,128,64,64) -> bf16 NHWC (Nb,64,64,128), optional per-(n,c)
// scale/shift. Local n. grid = Nb*64, 256 threads.
// ---------------------------------------------------------------------------
__global__ __launch_bounds__(256) void k_norm_transpose(
    const float* __restrict__ src,
    unsigned short* __restrict__ dst,
    const float2* __restrict__ scsh,
    int apply)
{
    __shared__ unsigned int tile[128 * 66];
    int b = blockIdx.x;
    int n = b >> 6, h = b & 63;
    int tid = threadIdx.x;
    #pragma unroll
    for (int i = 0; i < 8; ++i) {
        int u = tid + i * 256;              // u < 2048
        int c = u >> 4, w0 = (u & 15) * 4;
        float2 sc = apply ? scsh[n * 128 + c] : make_float2(1.f, 0.f);
        float4 v = *(const float4*)(src + ((size_t)(n * 128 + c) * 4096 + h * 64 + w0));
        tile[c * 66 + w0 + 0] = f2b(v.x * sc.x + sc.y);
        tile[c * 66 + w0 + 1] = f2b(v.y * sc.x + sc.y);
        tile[c * 66 + w0 + 2] = f2b(v.z * sc.x + sc.y);
        tile[c * 66 + w0 + 3] = f2b(v.w * sc.x + sc.y);
    }
    __syncthreads();
    #pragma unroll
    for (int i = 0; i < 32; ++i) {
        int idx = tid + i * 256;            // idx < 8192
        int c = idx & 127, w = idx >> 7;
        dst[((size_t)(n * 64 + h) * 64 + w) * 128 + c] = (unsigned short)tile[c * 66 + w];
    }
}

// ---------------------------------------------------------------------------
// Modulation GEMM + weight repack + bias GEMM. 512 threads.
// blocks 0..255: 8 waves = (khalf 0..1) x (rowgroup 0..3); each wave does
//   32 rows x 32 samples x K=256 slice; LDS reduce across khalf.
// blocks 256..287: bias[n][oc], K split 4 ways across tid>>7.
// ---------------------------------------------------------------------------
__global__ __launch_bounds__(512) void k_modbias(
    const float* __restrict__ t_w,   // (32768,512)
    const float* __restrict__ t_b,   // (32768)
    const float* __restrict__ Wc,    // (128,128,3,3)
    const float* __restrict__ tb_w,  // (128,512)
    const float* __restrict__ tb_b,  // (128)
    const float* __restrict__ bconv, // (128)
    const float* __restrict__ task,  // (32,512)
    unsigned short* __restrict__ Wmod, // (32,9,128,128) bf16
    float* __restrict__ bias)          // (32,128)
{
    __shared__ float accbuf[4][64][16];   // 16 KB
    __shared__ float gb[32 * 130];        // 16.6 KB
    __shared__ float red[512];            // 2 KB
    int blk = blockIdx.x;
    int tid = threadIdx.x;

    if (blk < 256) {
        int wv = tid >> 6, lane = tid & 63, l31 = lane & 31, lhalf = lane >> 5;
        int rg = wv & 3, kh2 = wv >> 2;
        int row = blk * 128 + rg * 32 + l31;
        const float* Ap = t_w + (size_t)row * 512 + kh2 * 256 + lhalf * 8;
        const float* Bp = task + l31 * 512 + kh2 * 256 + lhalf * 8;
        f32x16 acc;
        #pragma unroll
        for (int e = 0; e < 16; ++e) acc[e] = 0.f;
        #pragma unroll 4
        for (int k0 = 0; k0 < 256; k0 += 16) {
            s16x8 a = cvt8(Ap + k0);
            s16x8 b = cvt8(Bp + k0);
            acc = __builtin_amdgcn_mfma_f32_32x32x16_bf16(a, b, acc, 0, 0, 0);
        }
        if (kh2) {
            #pragma unroll
            for (int e = 0; e < 16; ++e) accbuf[rg][lane][e] = acc[e];
        }
        __syncthreads();
        if (!kh2) {
            int nn = l31;
            #pragma unroll
            for (int reg = 0; reg < 16; ++reg) {
                int rl = rg * 32 + (reg & 3) + 8 * (reg >> 2) + 4 * lhalf;
                float v = (acc[reg] + accbuf[rg][lane][reg]) * 0.0625f
                        + t_b[blk * 128 + rl];
                gb[nn * 130 + rl] = v;
            }
        }
        __syncthreads();
        for (int it = 0; it < 36; ++it) {
            int u = tid + it * 512;          // < 18432 = 32n*9tap*64oi
            int n2 = u / 576;
            int rem = u - n2 * 576;
            int tap = rem >> 6, oi = rem & 63;
            int oig = blk * 64 + oi;
            float gamma = gb[n2 * 130 + 2 * oi];
            float beta  = gb[n2 * 130 + 2 * oi + 1];
            float val = (Wc[oig * 9 + tap] * gamma + beta) * (1.0f / 24.0f);
            Wmod[(size_t)(n2 * 9 + tap) * 16384 + oig] = (unsigned short)f2b(val);
        }
    } else {
        int n = blk - 256;
        int c = tid & 127, qk = tid >> 7;   // qk in 0..3
        const float* tw = tb_w + c * 512 + qk * 128;
        const float* tk = task + n * 512 + qk * 128;
        float s = 0.f;
        #pragma unroll
        for (int k0 = 0; k0 < 128; k0 += 4) {
            float4 a = *(const float4*)(tw + k0);
            float4 b = *(const float4*)(tk + k0);
            s += a.x * b.x + a.y * b.y + a.z * b.z + a.w * b.w;
        }
        red[tid] = s;
        __syncthreads();
        if (tid < 128)
            bias[n * 128 + tid] = bconv[tid]
                + (red[tid] + red[tid + 128] + red[tid + 256] + red[tid + 384]) * 0.0625f
                + tb_b[tid];
    }
}

// ---------------------------------------------------------------------------
// Per-sample modulated 3x3 conv (pad 1) + bias + noise + leakyReLU.
// Block = (n, 2 output rows): grid = Nb*32. 4 waves = (roww 0..1)x(ochalf).
// Wave tile: 64 oc x 64 pix (one row). acc[2][2] (64 f32/lane).
// LDS [4 rows][66 wslots][32 ci] bf16, XOR-swizzled 16B blocks.
// ---------------------------------------------------------------------------
__global__ __launch_bounds__(256, 4) void k_conv(
    const unsigned short* __restrict__ xT,
    const unsigned short* __restrict__ Wmod,
    const float* __restrict__ bias,
    const float* __restrict__ nzw,
    const float* __restrict__ noise,
    float* __restrict__ y)
{
    __shared__ __align__(16) unsigned short xs[4 * 66 * 32];
    int blk = blockIdx.x;
    int n = blk >> 5, r0 = (blk & 31) * 2;
    int tid = threadIdx.x;
    int wv = tid >> 6, lane = tid & 63, l31 = lane & 31, lhalf = lane >> 5;
    int ochalf = wv & 1, roww = wv >> 1;

    f32x16 acc[2][2];
    #pragma unroll
    for (int a = 0; a < 2; ++a)
        #pragma unroll
        for (int t = 0; t < 2; ++t)
            #pragma unroll
            for (int e = 0; e < 16; ++e) acc[a][t][e] = 0.f;

    for (int cic = 0; cic < 4; ++cic) {
        __syncthreads();
        #pragma unroll
        for (int i = 0; i < 5; ++i) {
            int u = tid + i * 256;
            if (u < 1056) {                    // 4 rows * 66 wsl * 4 blocks
                int row = u / 264;
                int rem = u - row * 264;
                int wsl = rem >> 2, bb = rem & 3;
                int h = r0 - 1 + row, wg = wsl - 1;
                uint4 v = make_uint4(0u, 0u, 0u, 0u);
                if (h >= 0 && h < 64 && wg >= 0 && wg < 64)
                    v = *(const uint4*)(xT + (((size_t)(n * 64 + h) * 64 + wg) * 128 + cic * 32 + bb * 8));
                int bs = bb ^ ((wsl >> 1) & 3);
                *(uint4*)((char*)xs + (row * 66 + wsl) * 64 + bs * 16) = v;
            }
        }
        __syncthreads();
        #pragma unroll
        for (int kh = 0; kh < 3; ++kh) {
            #pragma unroll
            for (int kw = 0; kw < 3; ++kw) {
                const unsigned short* wp = Wmod + (size_t)(n * 9 + kh * 3 + kw) * 16384;
                #pragma unroll
                for (int ks = 0; ks < 2; ++ks) {
                    int ci = cic * 32 + ks * 16 + lhalf * 8;
                    s16x8 A0 = *(const s16x8*)(wp + (ochalf * 64 + l31) * 128 + ci);
                    s16x8 A1 = *(const s16x8*)(wp + (ochalf * 64 + 32 + l31) * 128 + ci);
                    int bb = ks * 2 + lhalf;
                    s16x8 Bf[2];
                    #pragma unroll
                    for (int t = 0; t < 2; ++t) {
                        int rl = roww + kh;                 // 0..3
                        int wsl = t * 32 + l31 + kw;
                        int bs = bb ^ ((wsl >> 1) & 3);
                        Bf[t] = *(const s16x8*)((const char*)xs + (rl * 66 + wsl) * 64 + bs * 16);
                    }
                    #pragma unroll
                    for (int t = 0; t < 2; ++t) {
                        acc[0][t] = __builtin_amdgcn_mfma_f32_32x32x16_bf16(A0, Bf[t], acc[0][t], 0, 0, 0);
                        acc[1][t] = __builtin_amdgcn_mfma_f32_32x32x16_bf16(A1, Bf[t], acc[1][t], 0, 0, 0);
                    }
                }
            }
        }
    }
    int r = r0 + roww;
    #pragma unroll
    for (int a = 0; a < 2; ++a) {
        int ocb = ochalf * 64 + a * 32;
        float bv[16], nzv[16];
        #pragma unroll
        for (int reg = 0; reg < 16; ++reg) {
            int oc = ocb + (reg & 3) + 8 * (reg >> 2) + 4 * lhalf;
            bv[reg] = bias[n * 128 + oc];
            nzv[reg] = nzw[oc] * 0.125f;
        }
        #pragma unroll
        for (int t = 0; t < 2; ++t) {
            int wq = t * 32 + l31;
            float nv = noise[(n * 64 + r) * 64 + wq];
            #pragma unroll
            for (int reg = 0; reg < 16; ++reg) {
                int oc = ocb + (reg & 3) + 8 * (reg >> 2) + 4 * lhalf;
                float v = acc[a][t][reg] + bv[reg] + nzv[reg] * nv;
                v = v > 0.f ? v : 0.2f * v;
                y[(size_t)(n * 128 + oc) * 4096 + r * 64 + wq] = v;
            }
        }
    }
}

// ---------------------------------------------------------------------------
// Per-(n,c) sum / sum-sq over 4096 fp32. grid = Nb*128.
// ---------------------------------------------------------------------------
__global__ __launch_bounds__(256) void k_stats(
    const float* __restrict__ y, float2* __restrict__ stats)
{
    __shared__ float rs[4], rs2[4];
    int blk = blockIdx.x, tid = threadIdx.x;
    const float4* p = (const float4*)(y + (size_t)blk * 4096) + tid * 4;
    float s = 0.f, s2 = 0.f;
    #pragma unroll
    for (int j = 0; j < 4; ++j) {
        float4 v = p[j];
        s  += v.x + v.y + v.z + v.w;
        s2 += v.x * v.x + v.y * v.y + v.z * v.z + v.w * v.w;
    }
    #pragma unroll
    for (int off = 32; off > 0; off >>= 1) {
        s  += __shfl_down(s, off);
        s2 += __shfl_down(s2, off);
    }
    int wv = tid >> 6;
    if ((tid & 63) == 0) { rs[wv] = s; rs2[wv] = s2; }
    __syncthreads();
    if (tid == 0)
        stats[blk] = make_float2(rs[0] + rs[1] + rs[2] + rs[3],
                                 rs2[0] + rs2[1] + rs2[2] + rs2[3]);
}

// ---------------------------------------------------------------------------
// Style GEMM + instance-norm finalize. grid = Nb.
// ---------------------------------------------------------------------------
__global__ __launch_bounds__(256) void k_finstyle(
    const float* __restrict__ style,
    const float* __restrict__ ad_w,
    const float* __restrict__ ad_b,
    const float2* __restrict__ stats,
    float2* __restrict__ scsh)
{
    __shared__ float styl[512];
    __shared__ float sbuf[256];
    int n = blockIdx.x, tid = threadIdx.x;
    styl[tid]       = style[n * 512 + tid];
    styl[tid + 256] = style[n * 512 + 256 + tid];
    __syncthreads();
    const float* wr = ad_w + tid * 512;
    float dot = 0.f;
    for (int k0 = 0; k0 < 512; k0 += 4) {
        float4 a = *(const float4*)(wr + k0);
        dot += a.x * styl[k0] + a.y * styl[k0 + 1] + a.z * styl[k0 + 2] + a.w * styl[k0 + 3];
    }
    sbuf[tid] = dot * 0.0625f + ad_b[tid];
    __syncthreads();
    if (tid < 128) {
        float gamma = sbuf[tid], beta = sbuf[128 + tid];
        float2 st = stats[n * 128 + tid];
        float mu = st.x * (1.f / 4096.f);
        float var = st.y * (1.f / 4096.f) - mu * mu;
        float rstd = rsqrtf(var + 1e-5f);
        float scale = gamma * rstd;
        scsh[n * 128 + tid] = make_float2(scale, beta - mu * scale);
    }
}

// ---------------------------------------------------------------------------
// Final AdaIN normalize fp32 NCHW -> fp32 NCHW. 4 floats/thread.
// ---------------------------------------------------------------------------
__global__ __launch_bounds__(256) void k_norm_out(
    const float* __restrict__ y,
    const float2* __restrict__ scsh,
    float* __restrict__ out)
{
    int idx = blockIdx.x * 256 + threadIdx.x;
    size_t base = (size_t)idx * 4;
    int c = (int)((base >> 12) & 127);
    int n = (int)(base >> 19);
    float2 sc = scsh[n * 128 + c];
    float4 v = *(const float4*)(y + base);
    float4 o;
    o.x = v.x * sc.x + sc.y; o.y = v.y * sc.x + sc.y;
    o.z = v.z * sc.x + sc.y; o.w = v.w * sc.x + sc.y;
    *(float4*)(out + base) = o;
}

// ---------------------------------------------------------------------------
extern "C" void kernel_launch(void* const* d_in, const int* in_sizes, int n_in,
                              void* d_out, int out_size, void* d_ws, size_t ws_size,
                              hipStream_t stream)
{
    const float* x     = (const float*)d_in[0];
    const float* style = (const float*)d_in[1];
    const float* noise = (const float*)d_in[2];
    const float* task  = (const float*)d_in[3];
    const float* W1    = (const float*)d_in[4];
    const float* b1    = (const float*)d_in[5];
    const float* t1w   = (const float*)d_in[6];
    const float* t1b   = (const float*)d_in[7];
    const float* tb1w  = (const float*)d_in[8];
    const float* tb1b  = (const float*)d_in[9];
    const float* nz1   = (const float*)d_in[10];
    const float* ad1w  = (const float*)d_in[11];
    const float* ad1b  = (const float*)d_in[12];
    const float* W2    = (const float*)d_in[13];
    const float* b2v   = (const float*)d_in[14];
    const float* t2w   = (const float*)d_in[15];
    const float* t2b   = (const float*)d_in[16];
    const float* tb2w  = (const float*)d_in[17];
    const float* tb2b  = (const float*)d_in[18];
    const float* nz2   = (const float*)d_in[19];
    const float* ad2w  = (const float*)d_in[20];
    const float* ad2b  = (const float*)d_in[21];
    float* outF = (float*)d_out;
    unsigned short* outU = (unsigned short*)d_out;  // bf16 NHWC staging inside d_out

    // Adaptive sample-grouping: pick smallest G whose Y-buffer fits ws.
    const size_t WMOD_B = 9437184;            // 32 samples bf16 modulated weights
    const size_t TAIL_B = 16384 + 32768 + 32768;
    int G = 4;
    if (ws_size >= WMOD_B + TAIL_B + 67108864)      G = 1;
    else if (ws_size >= WMOD_B + TAIL_B + 33554432) G = 2;
    const int NBS = 32 / G;                   // samples per group

    char* ws = (char*)d_ws;
    unsigned short* WMOD  = (unsigned short*)ws;
    float*          YQ    = (float*)(ws + WMOD_B);
    char* tail = ws + WMOD_B + (size_t)67108864 / G;
    float*  BIAS  = (float*)tail;
    float2* STATS = (float2*)(tail + 16384);
    float2* SCSH  = (float2*)(tail + 16384 + 32768);

    const size_t NS  = 524288;   // per-sample activation elements
    const size_t WMS = 147456;   // per-sample Wmod elements

    // stage 0: fp32 NCHW x -> bf16 NHWC (all 32 samples) into d_out
    k_norm_transpose<<<2048, 256, 0, stream>>>(x, outU, nullptr, 0);

    // ---- layer 1 (groups ascending; NHWC replaced in-place per group) ----
    k_modbias<<<288, 512, 0, stream>>>(t1w, t1b, W1, tb1w, tb1b, b1, task, WMOD, BIAS);
    for (int q = 0; q < G; ++q) {
        int n0 = q * NBS;
        k_conv<<<NBS * 32, 256, 0, stream>>>(outU + n0 * NS, WMOD + n0 * WMS,
                                             BIAS + n0 * 128, nz1, noise + n0 * 4096, YQ);
        k_stats<<<NBS * 128, 256, 0, stream>>>(YQ, STATS + n0 * 128);
        k_finstyle<<<NBS, 256, 0, stream>>>(style + n0 * 512, ad1w, ad1b,
                                            STATS + n0 * 128, SCSH + n0 * 128);
        k_norm_transpose<<<NBS * 64, 256, 0, stream>>>(YQ, outU + n0 * NS,
                                                       SCSH + n0 * 128, 1);
    }

    // ---- layer 2 (groups DESCENDING: fp32 outputs into d_out never clobber
    //      bf16 NHWC regions still needed by lower groups) ----
    k_modbias<<<288, 512, 0, stream>>>(t2w, t2b, W2, tb2w, tb2b, b2v, task, WMOD, BIAS);
    for (int q = G - 1; q >= 0; --q) {
        int n0 = q * NBS;
        k_conv<<<NBS * 32, 256, 0, stream>>>(outU + n0 * NS, WMOD + n0 * WMS,
                                             BIAS + n0 * 128, nz2, noise + n0 * 4096, YQ);
        k_stats<<<NBS * 128, 256, 0, stream>>>(YQ, STATS + n0 * 128);
        k_finstyle<<<NBS, 256, 0, stream>>>(style + n0 * 512, ad2w, ad2b,
                                            STATS + n0 * 128, SCSH + n0 * 128);
        k_norm_out<<<NBS * 512, 256, 0, stream>>>(YQ, SCSH + n0 * 128,
                                                  outF + n0 * NS);
    }
}